// Round 9
// baseline (232.306 us; speedup 1.0000x reference)
//
#include <hip/hip_runtime.h>
#include <hip/hip_fp16.h>
#include <math.h>

#define NDIM 1024
#define KDIM 64
#define BDIM 256
#define BKDIM 16384

typedef unsigned short u16;
typedef __attribute__((ext_vector_type(8))) short bf16x8;
typedef __attribute__((ext_vector_type(4))) short bf16x4;
typedef __attribute__((ext_vector_type(4))) float f32x4;

__device__ __forceinline__ float bf2f(u16 u) {
  union { unsigned u; float f; } x; x.u = ((unsigned)u) << 16; return x.f;
}
__device__ __forceinline__ u16 f2bf(float f) {
  union { float f; unsigned u; } x; x.f = f;
  unsigned u = x.u;
  u += 0x7fffu + ((u >> 16) & 1u);   // RNE
  return (u16)(u >> 16);
}

// async 16B global->LDS (DMA, no VGPR roundtrip). LDS side must be
// wave-uniform base + lane*16; global side is per-lane (free gather).
__device__ __forceinline__ void async16(const u16* g, u16* s) {
  __builtin_amdgcn_global_load_lds(
      (const __attribute__((address_space(1))) unsigned int*)g,
      (__attribute__((address_space(3))) unsigned int*)s,
      16, 0, 0);
}

// ------ K_PRE: blocks [0,1024) = row logsumexp of A_logits/T;
//               blocks [1024,2048) = W sinkhorn (verbatim bodies, merged to
//               cut a launch gap; both depend on nothing). --------------------
__global__ __launch_bounds__(256) void k_pre(const float* __restrict__ Alog,
                                             float* __restrict__ r,
                                             const float* __restrict__ W1,
                                             const float* __restrict__ WV,
                                             u16* __restrict__ Wt) {
  __shared__ float sred[256];
  __shared__ float sla[64 * 65];
  int t = threadIdx.x;
  if (blockIdx.x < 1024) {
    // ---- row logsumexp ----
    int m = blockIdx.x;
    float v[4], mx = -3.0e38f;
#pragma unroll
    for (int j = 0; j < 4; j++) {
      v[j] = Alog[m * NDIM + t + j * 256] * 5.0f;
      mx = fmaxf(mx, v[j]);
    }
    sred[t] = mx; __syncthreads();
    for (int s = 128; s > 0; s >>= 1) { if (t < s) sred[t] = fmaxf(sred[t], sred[t + s]); __syncthreads(); }
    float bm = sred[0]; __syncthreads();
    float sm = 0.f;
#pragma unroll
    for (int j = 0; j < 4; j++) sm += __expf(v[j] - bm);
    sred[t] = sm; __syncthreads();
    for (int s = 128; s > 0; s >>= 1) { if (t < s) sred[t] += sred[t + s]; __syncthreads(); }
    if (t == 0) r[m] = bm + __logf(sred[0]);
  } else {
    // ---- W_logits = W1@WV, per-block sinkhorn, Wt[t][o][i] bf16 ----
    int tb = blockIdx.x - 1024;
    int d = t >> 2, q = t & 3;      // row d, col segment q*16..q*16+15
    float w1[8];
#pragma unroll
    for (int k = 0; k < 8; k++) w1[k] = W1[tb * 8 + k];
    float la[16];
#pragma unroll
    for (int j = 0; j < 16; j++) la[j] = 0.f;
#pragma unroll
    for (int k = 0; k < 8; k++) {
      float wk = w1[k];
      const float4* base = (const float4*)&WV[k * 4096 + d * 64 + q * 16];
#pragma unroll
      for (int v = 0; v < 4; v++) {
        float4 f = base[v];
        la[v * 4 + 0] += wk * f.x; la[v * 4 + 1] += wk * f.y;
        la[v * 4 + 2] += wk * f.z; la[v * 4 + 3] += wk * f.w;
      }
    }
    float mx = -3.0e38f;
#pragma unroll
    for (int j = 0; j < 16; j++) { la[j] *= 5.0f; mx = fmaxf(mx, la[j]); }
    float sm = 0.f;
#pragma unroll
    for (int j = 0; j < 16; j++) sm += __expf(la[j] - mx);
    for (int off = 1; off < 4; off <<= 1) {   // combine 4 lanes of a row
      float mo = __shfl_xor(mx, off), so = __shfl_xor(sm, off);
      float mn = fmaxf(mx, mo);
      sm = sm * __expf(mx - mn) + so * __expf(mo - mn);
      mx = mn;
    }
    float rl = mx + __logf(sm);
#pragma unroll
    for (int j = 0; j < 16; j++) sla[d * 65 + q * 16 + j] = la[j] - rl;
    __syncthreads();
    int e = t >> 2, jj = t & 3;     // col e, row segment jj*16..jj*16+15
    float lb[16]; float m2 = -3.0e38f;
#pragma unroll
    for (int i = 0; i < 16; i++) { lb[i] = sla[(jj * 16 + i) * 65 + e]; m2 = fmaxf(m2, lb[i]); }
    float s2 = 0.f;
#pragma unroll
    for (int i = 0; i < 16; i++) s2 += __expf(lb[i] - m2);
    for (int off = 1; off < 4; off <<= 1) {
      float mo = __shfl_xor(m2, off), so = __shfl_xor(s2, off);
      float mn = fmaxf(m2, mo);
      s2 = s2 * __expf(m2 - mn) + so * __expf(mo - mn);
      m2 = mn;
    }
    float cl = m2 + __logf(s2);
#pragma unroll
    for (int i = 0; i < 16; i++)
      Wt[tb * 4096 + e * 64 + jj * 16 + i] = f2bf(__expf(lb[i] - cl));  // Wt[t][o][i]=W[i][o]
  }
}

// ------ K4 v5 (unchanged from round 8): x_local = x@W, row-major xln[bk][m].
__global__ __launch_bounds__(512, 4) void k_gemm1d(const float* __restrict__ x,
                                                   const u16* __restrict__ Wt,
                                                   u16* __restrict__ xln) {
  int bx = blockIdx.x, bt = blockIdx.y, t = threadIdx.x;
  int n8 = (bx & 15) * 8 + (bx >> 4);   // bijective; line-group g = bx&15
  int w = t >> 6, l = t & 63, q = l >> 4, lr = l & 15;
  int p = w & 3, h = w >> 2;            // b-subrange, n-half
  int nb = n8 * 8 + h * 4;
  const float* xb = x + (size_t)(bt * 64 + p * 16 + lr) * 65536;
  f32x4 acc[4][4] = {};
#pragma unroll
  for (int np = 0; np < 4; np++) {
    int n = nb + np;
#pragma unroll
    for (int ks = 0; ks < 2; ks++) {
      const float* xr = xb + n * 64 + ks * 32 + q * 8;
      float4 v0 = *(const float4*)xr;
      float4 v1 = *(const float4*)(xr + 4);
      float vf[8] = {v0.x, v0.y, v0.z, v0.w, v1.x, v1.y, v1.z, v1.w};
      bf16x8 ah, al;
#pragma unroll
      for (int j = 0; j < 8; j++) {
        u16 hh = f2bf(vf[j]);
        ah[j] = (short)hh;
        al[j] = (short)f2bf(vf[j] - bf2f(hh));
      }
#pragma unroll
      for (int ni = 0; ni < 4; ni++) {
        bf16x8 bfr = *(const bf16x8*)&Wt[(size_t)n * 4096 + (ni * 16 + lr) * 64 + ks * 32 + q * 8];
        acc[np][ni] = __builtin_amdgcn_mfma_f32_16x16x32_bf16(ah, bfr, acc[np][ni], 0, 0, 0);
        acc[np][ni] = __builtin_amdgcn_mfma_f32_16x16x32_bf16(al, bfr, acc[np][ni], 0, 0, 0);
      }
    }
  }
#pragma unroll
  for (int ni = 0; ni < 4; ni++) {
#pragma unroll
    for (int reg = 0; reg < 4; reg++) {
      int bk = (bt * 64 + p * 16 + q * 4 + reg) * 64 + ni * 16 + lr;
      bf16x4 o;
#pragma unroll
      for (int np = 0; np < 4; np++) o[np] = (short)f2bf(acc[np][ni][reg]);
      *(bf16x4*)&xln[(size_t)bk * 1024 + nb] = o;   // 8B half-chunk of row bk
    }
  }
}

// ------ K_POST (unchanged from round 8): col logsumexp+Dt'/gA/bA ∪ LN stats.
__global__ __launch_bounds__(256) void k_post(const float* __restrict__ Alog,
                                              const float* __restrict__ r,
                                              const float* __restrict__ g2,
                                              const float* __restrict__ b2,
                                              u16* __restrict__ Dt,
                                              float* __restrict__ gAc,
                                              float* __restrict__ bAc,
                                              const u16* __restrict__ xln,
                                              float* __restrict__ e1,
                                              float* __restrict__ e2,
                                              float* __restrict__ e3) {
  __shared__ float sred[256];
  int t = threadIdx.x;
  if (blockIdx.x < 1024) {
    // ---- col logsumexp; Dt'[n][m] = gamma[m]*(A[m][n]-1/N); gA; bA ----
    int n = blockIdx.x;
    float v[4], mx = -3.0e38f;
#pragma unroll
    for (int j = 0; j < 4; j++) {
      int m = t + j * 256;
      v[j] = Alog[m * NDIM + n] * 5.0f - r[m];
      mx = fmaxf(mx, v[j]);
    }
    sred[t] = mx; __syncthreads();
    for (int s = 128; s > 0; s >>= 1) { if (t < s) sred[t] = fmaxf(sred[t], sred[t + s]); __syncthreads(); }
    float bm = sred[0]; __syncthreads();
    float sm = 0.f;
#pragma unroll
    for (int j = 0; j < 4; j++) sm += __expf(v[j] - bm);
    sred[t] = sm; __syncthreads();
    for (int s = 128; s > 0; s >>= 1) { if (t < s) sred[t] += sred[t + s]; __syncthreads(); }
    float cn = bm + __logf(sred[0]);
    float ga = 0.f, ba = 0.f;
#pragma unroll
    for (int j = 0; j < 4; j++) {
      int m = t + j * 256;
      float e = __expf(v[j] - cn);
      float gm = g2[m];
      Dt[n * NDIM + m] = f2bf(gm * (e - 0.0009765625f));
      ga += gm * e; ba += b2[m] * e;
    }
    __syncthreads();
    sred[t] = ga; __syncthreads();
    for (int s = 128; s > 0; s >>= 1) { if (t < s) sred[t] += sred[t + s]; __syncthreads(); }
    if (t == 0) gAc[n] = sred[0];
    __syncthreads();
    sred[t] = ba; __syncthreads();
    for (int s = 128; s > 0; s >>= 1) { if (t < s) sred[t] += sred[t + s]; __syncthreads(); }
    if (t == 0) bAc[n] = sred[0];
  } else {
    // ---- LN stats per bk row -> e1/e2/e3 ----
    int row = (blockIdx.x - 1024) * 16 + (t >> 4);
    int c = t & 15;
    const u16* xr = xln + (size_t)row * 1024 + c * 8;
    float S = 0.f, Q = 0.f, W = 0.f;
#pragma unroll
    for (int j = 0; j < 8; j++) {
      bf16x8 v = *(const bf16x8*)&xr[j * 128];
      const float* gp = g2 + j * 128 + c * 8;
      float4 g0 = *(const float4*)gp;
      float4 g1 = *(const float4*)(gp + 4);
      float gg[8] = {g0.x, g0.y, g0.z, g0.w, g1.x, g1.y, g1.z, g1.w};
#pragma unroll
      for (int k = 0; k < 8; k++) {
        float f = bf2f((u16)v[k]);
        S += f; Q += f * f; W += f * gg[k];
      }
    }
#pragma unroll
    for (int off = 1; off < 16; off <<= 1) {
      S += __shfl_xor(S, off);
      Q += __shfl_xor(Q, off);
      W += __shfl_xor(W, off);
    }
    if (c == 0) {
      float m_ = S * (1.0f / 1024.0f);
      float var = Q * (1.0f / 1024.0f) - m_ * m_;
      float a = rsqrtf(var + 1e-5f);
      e1[row] = a;
      e2[row] = a * W * (1.0f / 1024.0f);
      e3[row] = -a * m_;
    }
  }
}

// ------ K6 v8: T3-minimal 2-phase double-buffered pipeline, BK=32.
// stage(kt+1) issued BEFORE compute(kt); one __syncthreads per iter (its
// implicit vmcnt(0) drain lands AFTER the compute phase -> HBM latency of
// the prefetch overlaps ds_read+MFMA). 4 x 8KB buffers = same 32KB LDS ->
// same 5 blk/CU occupancy (round-3 lesson). Swizzle re-derived for 4-chunk
// rows: stage src chunk c = (l&3)^((l>>2)&3), read chunk pc = q^(lr&3) —
// same involution family / mod-128B bank profile as the proven 0-conflict
// 64-m scheme. Race-safety of single barrier: each wave's ds_reads are
// consumed by its MFMAs before it reaches the barrier, so next iter's DMA
// into the just-read buffer is ordered. Epilogue identical to round 8.
__global__ __launch_bounds__(256) void k_gemm2h(const u16* __restrict__ Dt,
                                                const u16* __restrict__ xln,
                                                const float* __restrict__ e1,
                                                const float* __restrict__ e2,
                                                const float* __restrict__ e3,
                                                const float* __restrict__ gAc,
                                                const float* __restrict__ bAc,
                                                float* __restrict__ out) {
  __shared__ __align__(16) u16 lA[2][128 * 32];  // [buf][n2_local][m32], swizzled
  __shared__ __align__(16) u16 lB[2][128 * 32];  // [buf][bk_local][m32], swizzled
  int bkt = blockIdx.x, n2t = blockIdx.y;
  int t = threadIdx.x, w = t >> 6, l = t & 63;
  int q = l >> 4, lr = l & 15;
  const u16* gA0 = Dt  + (size_t)(n2t * 128) * NDIM;
  const u16* gB0 = xln + (size_t)(bkt * 128) * NDIM;
  // per-lane stage geometry: row-in-64 = w*16 + (l>>2), phys chunk = l&3,
  // logical source chunk = (l&3) ^ ((l>>2)&3)
  int srow = w * 16 + (l >> 2);
  int scol = (((l & 3) ^ ((l >> 2) & 3))) * 8;
  int sdst = (w * 16) * 32 + l * 8;              // wave-uniform base + lane*16B
  int pc = (q ^ (lr & 3)) * 8;                   // read-side phys chunk offset

  f32x4 acc[4][4] = {};
  // prologue: stage kt=0 into buf0
#pragma unroll
  for (int j = 0; j < 2; j++) {
    async16(gA0 + (size_t)(j * 64 + srow) * NDIM + scol, &lA[0][j * 2048 + sdst]);
    async16(gB0 + (size_t)(j * 64 + srow) * NDIM + scol, &lB[0][j * 2048 + sdst]);
  }
  __syncthreads();   // drains vmcnt -> buf0 ready

#pragma unroll 2
  for (int kt = 0; kt < 32; kt++) {
    int cur = kt & 1;
    if (kt < 31) {   // issue prefetch of kt+1 into the other buffer
      int nxt = cur ^ 1;
      int mo = (kt + 1) * 32 + scol;
#pragma unroll
      for (int j = 0; j < 2; j++) {
        async16(gA0 + (size_t)(j * 64 + srow) * NDIM + mo, &lA[nxt][j * 2048 + sdst]);
        async16(gB0 + (size_t)(j * 64 + srow) * NDIM + mo, &lB[nxt][j * 2048 + sdst]);
      }
    }
    // compute current buffer
    bf16x8 af[4], bfr[4];
#pragma unroll
    for (int mi = 0; mi < 4; mi++)
      af[mi] = *(const bf16x8*)&lA[cur][((w >> 1) * 64 + mi * 16 + lr) * 32 + pc];
#pragma unroll
    for (int ni = 0; ni < 4; ni++)
      bfr[ni] = *(const bf16x8*)&lB[cur][((w & 1) * 64 + ni * 16 + lr) * 32 + pc];
#pragma unroll
    for (int mi = 0; mi < 4; mi++)
#pragma unroll
      for (int ni = 0; ni < 4; ni++)
        acc[mi][ni] = __builtin_amdgcn_mfma_f32_16x16x32_bf16(af[mi], bfr[ni], acc[mi][ni], 0, 0, 0);
    __syncthreads();  // drains vmcnt (prefetch landed) + orders LDS reuse
  }

  // Stage epilogue operands into dead LDS (2.5KB): [0)e1 [128)e2 [256)e3 [384)gA [512)bA
  float* sE = (float*)&lA[0][0];
  if (t < 128) {
    sE[t]       = e1[bkt * 128 + t];
    sE[128 + t] = e2[bkt * 128 + t];
    sE[256 + t] = e3[bkt * 128 + t];
    sE[384 + t] = gAc[n2t * 128 + t];
    sE[512 + t] = bAc[n2t * 128 + t];
  }
  __syncthreads();
  // 12 per-bk scalars hoisted once (invariant across the outer n2 loop):
  float a1v[4], a2v[4], a3v[4];
#pragma unroll
  for (int ni = 0; ni < 4; ni++) {
    int bkl = (w & 1) * 64 + ni * 16 + lr;       // local bk 0..127
    a1v[ni] = sE[bkl]; a2v[ni] = sE[128 + bkl]; a3v[ni] = sE[256 + bkl];
  }
  int bkb = bkt * 128 + (w & 1) * 64 + lr;       // bk for ni=0
#pragma unroll
  for (int mi = 0; mi < 4; mi++) {
    __builtin_amdgcn_sched_barrier(0);           // pin sE reads per mi group
#pragma unroll
    for (int reg = 0; reg < 4; reg++) {
      int n2l = (w >> 1) * 64 + mi * 16 + q * 4 + reg;   // local n2 0..127
      float gg = sE[384 + n2l], bb = sE[512 + n2l];
      int n2 = n2t * 128 + n2l;
#pragma unroll
      for (int ni = 0; ni < 4; ni++) {
        int bk = bkb + ni * 16;
        int b = bk >> 6, o = bk & 63;
        out[(size_t)b * 65536 + n2 * 64 + o] =
            a1v[ni] * acc[mi][ni][reg] + a2v[ni] + a3v[ni] * gg + bb;
      }
    }
  }
}

extern "C" void kernel_launch(void* const* d_in, const int* in_sizes, int n_in,
                              void* d_out, int out_size, void* d_ws, size_t ws_size,
                              hipStream_t stream) {
  const float* x    = (const float*)d_in[0];
  const float* Alog = (const float*)d_in[1];
  const float* W1   = (const float*)d_in[2];
  const float* WV   = (const float*)d_in[3];
  const float* g2   = (const float*)d_in[4];
  const float* b2   = (const float*)d_in[5];
  float* out = (float*)d_out;                       // fp32 output, 64 MiB
  char* ws = (char*)d_ws;

  u16*   xln = (u16*)(ws);                          // 32 MiB: [16384][1024] bf16
  u16*   Wt  = (u16*)(ws + 33554432ull);            //  8 MiB: [1024][4096] bf16 (dead after k_gemm1d)
  float* e1  = (float*)(ws + 33554432ull);          // 64 KiB, overlays Wt (written k_post > last Wt read)
  float* e2  = (float*)(ws + 33619968ull);          // 64 KiB
  float* e3  = (float*)(ws + 33685504ull);          // 64 KiB
  u16*   Dt  = (u16*)(ws + 41943040ull);            //  2 MiB: [1024][1024] bf16 (gamma-folded)
  float* r   = (float*)(ws + 44040192ull);          //  4 KiB
  float* gAc = (float*)(ws + 44044288ull);          //  4 KiB
  float* bAc = (float*)(ws + 44048384ull);          //  4 KiB

  k_pre<<<dim3(2048), dim3(256), 0, stream>>>(Alog, r, W1, WV, Wt);
  k_gemm1d<<<dim3(128, 4), dim3(512), 0, stream>>>(x, Wt, xln);
  k_post<<<dim3(2048), dim3(256), 0, stream>>>(Alog, r, g2, b2, Dt, gAc, bAc, xln, e1, e2, e3);
  k_gemm2h<<<dim3(128, 8), dim3(256), 0, stream>>>(Dt, xln, e1, e2, e3, gAc, bAc, out);
}

// Round 10
// 227.243 us; speedup vs baseline: 1.0223x; 1.0223x over previous
//
#include <hip/hip_runtime.h>
#include <hip/hip_fp16.h>
#include <hip/hip_bf16.h>
#include <math.h>

#define NDIM 1024
#define KDIM 64
#define BDIM 256
#define BKDIM 16384

typedef unsigned short u16;
typedef __attribute__((ext_vector_type(8))) short bf16x8;
typedef __attribute__((ext_vector_type(4))) short bf16x4;
typedef __attribute__((ext_vector_type(4))) float f32x4;

__device__ __forceinline__ float bf2f(u16 u) {
  union { unsigned u; float f; } x; x.u = ((unsigned)u) << 16; return x.f;
}
__device__ __forceinline__ u16 f2bf(float f) {
  union { float f; unsigned u; } x; x.f = f;
  unsigned u = x.u;
  u += 0x7fffu + ((u >> 16) & 1u);   // RNE
  return (u16)(u >> 16);
}
// native RNE f32->bf16 (gfx950 HW convert; bit-identical to f2bf for finite x)
__device__ __forceinline__ u16 f2bf_n(float f) {
  union { __hip_bfloat16 b; u16 u; } c;
  c.b = __float2bfloat16(f);
  return c.u;
}

// async 16B global->LDS (DMA, no VGPR roundtrip). LDS side must be
// wave-uniform base + lane*16; global side is per-lane (free gather).
__device__ __forceinline__ void async16(const u16* g, u16* s) {
  __builtin_amdgcn_global_load_lds(
      (const __attribute__((address_space(1))) unsigned int*)g,
      (__attribute__((address_space(3))) unsigned int*)s,
      16, 0, 0);
}

// ------ K_PRE: blocks [0,1024) = row logsumexp of A_logits/T;
//               blocks [1024,2048) = W sinkhorn (verbatim bodies, merged to
//               cut a launch gap; both depend on nothing). --------------------
__global__ __launch_bounds__(256) void k_pre(const float* __restrict__ Alog,
                                             float* __restrict__ r,
                                             const float* __restrict__ W1,
                                             const float* __restrict__ WV,
                                             u16* __restrict__ Wt) {
  __shared__ float sred[256];
  __shared__ float sla[64 * 65];
  int t = threadIdx.x;
  if (blockIdx.x < 1024) {
    // ---- row logsumexp ----
    int m = blockIdx.x;
    float v[4], mx = -3.0e38f;
#pragma unroll
    for (int j = 0; j < 4; j++) {
      v[j] = Alog[m * NDIM + t + j * 256] * 5.0f;
      mx = fmaxf(mx, v[j]);
    }
    sred[t] = mx; __syncthreads();
    for (int s = 128; s > 0; s >>= 1) { if (t < s) sred[t] = fmaxf(sred[t], sred[t + s]); __syncthreads(); }
    float bm = sred[0]; __syncthreads();
    float sm = 0.f;
#pragma unroll
    for (int j = 0; j < 4; j++) sm += __expf(v[j] - bm);
    sred[t] = sm; __syncthreads();
    for (int s = 128; s > 0; s >>= 1) { if (t < s) sred[t] += sred[t + s]; __syncthreads(); }
    if (t == 0) r[m] = bm + __logf(sred[0]);
  } else {
    // ---- W_logits = W1@WV, per-block sinkhorn, Wt[t][o][i] bf16 ----
    int tb = blockIdx.x - 1024;
    int d = t >> 2, q = t & 3;      // row d, col segment q*16..q*16+15
    float w1[8];
#pragma unroll
    for (int k = 0; k < 8; k++) w1[k] = W1[tb * 8 + k];
    float la[16];
#pragma unroll
    for (int j = 0; j < 16; j++) la[j] = 0.f;
#pragma unroll
    for (int k = 0; k < 8; k++) {
      float wk = w1[k];
      const float4* base = (const float4*)&WV[k * 4096 + d * 64 + q * 16];
#pragma unroll
      for (int v = 0; v < 4; v++) {
        float4 f = base[v];
        la[v * 4 + 0] += wk * f.x; la[v * 4 + 1] += wk * f.y;
        la[v * 4 + 2] += wk * f.z; la[v * 4 + 3] += wk * f.w;
      }
    }
    float mx = -3.0e38f;
#pragma unroll
    for (int j = 0; j < 16; j++) { la[j] *= 5.0f; mx = fmaxf(mx, la[j]); }
    float sm = 0.f;
#pragma unroll
    for (int j = 0; j < 16; j++) sm += __expf(la[j] - mx);
    for (int off = 1; off < 4; off <<= 1) {   // combine 4 lanes of a row
      float mo = __shfl_xor(mx, off), so = __shfl_xor(sm, off);
      float mn = fmaxf(mx, mo);
      sm = sm * __expf(mx - mn) + so * __expf(mo - mn);
      mx = mn;
    }
    float rl = mx + __logf(sm);
#pragma unroll
    for (int j = 0; j < 16; j++) sla[d * 65 + q * 16 + j] = la[j] - rl;
    __syncthreads();
    int e = t >> 2, jj = t & 3;     // col e, row segment jj*16..jj*16+15
    float lb[16]; float m2 = -3.0e38f;
#pragma unroll
    for (int i = 0; i < 16; i++) { lb[i] = sla[(jj * 16 + i) * 65 + e]; m2 = fmaxf(m2, lb[i]); }
    float s2 = 0.f;
#pragma unroll
    for (int i = 0; i < 16; i++) s2 += __expf(lb[i] - m2);
    for (int off = 1; off < 4; off <<= 1) {
      float mo = __shfl_xor(m2, off), so = __shfl_xor(s2, off);
      float mn = fmaxf(m2, mo);
      s2 = s2 * __expf(m2 - mn) + so * __expf(mo - mn);
      m2 = mn;
    }
    float cl = m2 + __logf(s2);
#pragma unroll
    for (int i = 0; i < 16; i++)
      Wt[tb * 4096 + e * 64 + jj * 16 + i] = f2bf(__expf(lb[i] - cl));  // Wt[t][o][i]=W[i][o]
  }
}

// ------ K4 v6: x_local = x@W, row-major xln[bk][m] bf16 (round-8 structure;
// round-9 change: native __float2bfloat16 casts replace manual RNE bit-ops
// in the hot loop — bit-identical for finite inputs, ~4x fewer VALU ops per
// conversion, ~384 conversions/thread).
__global__ __launch_bounds__(512, 4) void k_gemm1d(const float* __restrict__ x,
                                                   const u16* __restrict__ Wt,
                                                   u16* __restrict__ xln) {
  int bx = blockIdx.x, bt = blockIdx.y, t = threadIdx.x;
  int n8 = (bx & 15) * 8 + (bx >> 4);   // bijective; line-group g = bx&15
  int w = t >> 6, l = t & 63, q = l >> 4, lr = l & 15;
  int p = w & 3, h = w >> 2;            // b-subrange, n-half
  int nb = n8 * 8 + h * 4;
  const float* xb = x + (size_t)(bt * 64 + p * 16 + lr) * 65536;
  f32x4 acc[4][4] = {};
#pragma unroll
  for (int np = 0; np < 4; np++) {
    int n = nb + np;
#pragma unroll
    for (int ks = 0; ks < 2; ks++) {
      const float* xr = xb + n * 64 + ks * 32 + q * 8;
      float4 v0 = *(const float4*)xr;
      float4 v1 = *(const float4*)(xr + 4);
      float vf[8] = {v0.x, v0.y, v0.z, v0.w, v1.x, v1.y, v1.z, v1.w};
      bf16x8 ah, al;
#pragma unroll
      for (int j = 0; j < 8; j++) {
        u16 hh = f2bf_n(vf[j]);
        ah[j] = (short)hh;
        al[j] = (short)f2bf_n(vf[j] - bf2f(hh));
      }
#pragma unroll
      for (int ni = 0; ni < 4; ni++) {
        bf16x8 bfr = *(const bf16x8*)&Wt[(size_t)n * 4096 + (ni * 16 + lr) * 64 + ks * 32 + q * 8];
        acc[np][ni] = __builtin_amdgcn_mfma_f32_16x16x32_bf16(ah, bfr, acc[np][ni], 0, 0, 0);
        acc[np][ni] = __builtin_amdgcn_mfma_f32_16x16x32_bf16(al, bfr, acc[np][ni], 0, 0, 0);
      }
    }
  }
#pragma unroll
  for (int ni = 0; ni < 4; ni++) {
#pragma unroll
    for (int reg = 0; reg < 4; reg++) {
      int bk = (bt * 64 + p * 16 + q * 4 + reg) * 64 + ni * 16 + lr;
      bf16x4 o;
#pragma unroll
      for (int np = 0; np < 4; np++) o[np] = (short)f2bf_n(acc[np][ni][reg]);
      *(bf16x4*)&xln[(size_t)bk * 1024 + nb] = o;   // 8B half-chunk of row bk
    }
  }
}

// ------ K_POST (unchanged from round 8): col logsumexp+Dt'/gA/bA ∪ LN stats.
__global__ __launch_bounds__(256) void k_post(const float* __restrict__ Alog,
                                              const float* __restrict__ r,
                                              const float* __restrict__ g2,
                                              const float* __restrict__ b2,
                                              u16* __restrict__ Dt,
                                              float* __restrict__ gAc,
                                              float* __restrict__ bAc,
                                              const u16* __restrict__ xln,
                                              float* __restrict__ e1,
                                              float* __restrict__ e2,
                                              float* __restrict__ e3) {
  __shared__ float sred[256];
  int t = threadIdx.x;
  if (blockIdx.x < 1024) {
    // ---- col logsumexp; Dt'[n][m] = gamma[m]*(A[m][n]-1/N); gA; bA ----
    int n = blockIdx.x;
    float v[4], mx = -3.0e38f;
#pragma unroll
    for (int j = 0; j < 4; j++) {
      int m = t + j * 256;
      v[j] = Alog[m * NDIM + n] * 5.0f - r[m];
      mx = fmaxf(mx, v[j]);
    }
    sred[t] = mx; __syncthreads();
    for (int s = 128; s > 0; s >>= 1) { if (t < s) sred[t] = fmaxf(sred[t], sred[t + s]); __syncthreads(); }
    float bm = sred[0]; __syncthreads();
    float sm = 0.f;
#pragma unroll
    for (int j = 0; j < 4; j++) sm += __expf(v[j] - bm);
    sred[t] = sm; __syncthreads();
    for (int s = 128; s > 0; s >>= 1) { if (t < s) sred[t] += sred[t + s]; __syncthreads(); }
    float cn = bm + __logf(sred[0]);
    float ga = 0.f, ba = 0.f;
#pragma unroll
    for (int j = 0; j < 4; j++) {
      int m = t + j * 256;
      float e = __expf(v[j] - cn);
      float gm = g2[m];
      Dt[n * NDIM + m] = f2bf(gm * (e - 0.0009765625f));
      ga += gm * e; ba += b2[m] * e;
    }
    __syncthreads();
    sred[t] = ga; __syncthreads();
    for (int s = 128; s > 0; s >>= 1) { if (t < s) sred[t] += sred[t + s]; __syncthreads(); }
    if (t == 0) gAc[n] = sred[0];
    __syncthreads();
    sred[t] = ba; __syncthreads();
    for (int s = 128; s > 0; s >>= 1) { if (t < s) sred[t] += sred[t + s]; __syncthreads(); }
    if (t == 0) bAc[n] = sred[0];
  } else {
    // ---- LN stats per bk row -> e1/e2/e3 ----
    int row = (blockIdx.x - 1024) * 16 + (t >> 4);
    int c = t & 15;
    const u16* xr = xln + (size_t)row * 1024 + c * 8;
    float S = 0.f, Q = 0.f, W = 0.f;
#pragma unroll
    for (int j = 0; j < 8; j++) {
      bf16x8 v = *(const bf16x8*)&xr[j * 128];
      const float* gp = g2 + j * 128 + c * 8;
      float4 g0 = *(const float4*)gp;
      float4 g1 = *(const float4*)(gp + 4);
      float gg[8] = {g0.x, g0.y, g0.z, g0.w, g1.x, g1.y, g1.z, g1.w};
#pragma unroll
      for (int k = 0; k < 8; k++) {
        float f = bf2f((u16)v[k]);
        S += f; Q += f * f; W += f * gg[k];
      }
    }
#pragma unroll
    for (int off = 1; off < 16; off <<= 1) {
      S += __shfl_xor(S, off);
      Q += __shfl_xor(Q, off);
      W += __shfl_xor(W, off);
    }
    if (c == 0) {
      float m_ = S * (1.0f / 1024.0f);
      float var = Q * (1.0f / 1024.0f) - m_ * m_;
      float a = rsqrtf(var + 1e-5f);
      e1[row] = a;
      e2[row] = a * W * (1.0f / 1024.0f);
      e3[row] = -a * m_;
    }
  }
}

// ------ K6 v7 (REVERTED to round-8 code — the proven 52.5us / 0-conflict /
// 88-VGPR config. Round-9 lesson: the BK=32 double-buffer swizzle was an
// 8-way bank conflict (4.19M conflicts, +10us); the BK=64 single-buffer
// scheme's 128B row stride + 8-chunk XOR is what makes it conflict-free.)
__global__ __launch_bounds__(256) void k_gemm2g(const u16* __restrict__ Dt,
                                                const u16* __restrict__ xln,
                                                const float* __restrict__ e1,
                                                const float* __restrict__ e2,
                                                const float* __restrict__ e3,
                                                const float* __restrict__ gAc,
                                                const float* __restrict__ bAc,
                                                float* __restrict__ out) {
  __shared__ __align__(16) u16 lA[128 * 64];  // [n2_local][m], swizzled
  __shared__ __align__(16) u16 lB[128 * 64];  // [bk_local][m], swizzled
  int bkt = blockIdx.x, n2t = blockIdx.y;
  int t = threadIdx.x, w = t >> 6, l = t & 63;
  int q = l >> 4, lr = l & 15;
  int rr = l >> 3;                 // row within 8-row group (0..7)
  int cc = (l & 7) ^ rr;           // logical chunk this lane fetches
  const u16* gAp = Dt  + (size_t)(n2t * 128) * NDIM + cc * 8;
  const u16* gBp = xln + (size_t)(bkt * 128) * NDIM + cc * 8;
  f32x4 acc[4][4] = {};
  for (int kt = 0; kt < 16; kt++) {
#pragma unroll
    for (int j = 0; j < 4; j++) {
      int ci = j * 4 + w;
      int row = ci * 8 + rr;
      async16(gAp + (size_t)row * NDIM + kt * 64, &lA[ci * 512 + l * 8]);
      async16(gBp + (size_t)row * NDIM + kt * 64, &lB[ci * 512 + l * 8]);
    }
    __syncthreads();   // drains vmcnt (global_load_lds) per barrier semantics
#pragma unroll
    for (int ks = 0; ks < 2; ks++) {
      int pc = ((ks * 4 + q) ^ (lr & 7)) * 8;   // physical chunk offset (halves)
      bf16x8 af[4], bfr[4];
#pragma unroll
      for (int mi = 0; mi < 4; mi++)
        af[mi] = *(const bf16x8*)&lA[((w >> 1) * 64 + mi * 16 + lr) * 64 + pc];
#pragma unroll
      for (int ni = 0; ni < 4; ni++)
        bfr[ni] = *(const bf16x8*)&lB[((w & 1) * 64 + ni * 16 + lr) * 64 + pc];
#pragma unroll
      for (int mi = 0; mi < 4; mi++)
#pragma unroll
        for (int ni = 0; ni < 4; ni++)
          acc[mi][ni] = __builtin_amdgcn_mfma_f32_16x16x32_bf16(af[mi], bfr[ni], acc[mi][ni], 0, 0, 0);
    }
    __syncthreads();   // tile consumed before next iter's DMA overwrites
  }
  // Stage epilogue operands into dead lA (2.5KB): [0)e1 [128)e2 [256)e3 [384)gA [512)bA
  float* sE = (float*)lA;
  if (t < 128) {
    sE[t]       = e1[bkt * 128 + t];
    sE[128 + t] = e2[bkt * 128 + t];
    sE[256 + t] = e3[bkt * 128 + t];
    sE[384 + t] = gAc[n2t * 128 + t];
    sE[512 + t] = bAc[n2t * 128 + t];
  }
  __syncthreads();
  // 12 per-bk scalars hoisted once (invariant across the outer n2 loop):
  float a1v[4], a2v[4], a3v[4];
#pragma unroll
  for (int ni = 0; ni < 4; ni++) {
    int bkl = (w & 1) * 64 + ni * 16 + lr;       // local bk 0..127
    a1v[ni] = sE[bkl]; a2v[ni] = sE[128 + bkl]; a3v[ni] = sE[256 + bkl];
  }
  int bkb = bkt * 128 + (w & 1) * 64 + lr;       // bk for ni=0
#pragma unroll
  for (int mi = 0; mi < 4; mi++) {
    __builtin_amdgcn_sched_barrier(0);           // pin sE reads per mi group
#pragma unroll
    for (int reg = 0; reg < 4; reg++) {
      int n2l = (w >> 1) * 64 + mi * 16 + q * 4 + reg;   // local n2 0..127
      float gg = sE[384 + n2l], bb = sE[512 + n2l];
      int n2 = n2t * 128 + n2l;
#pragma unroll
      for (int ni = 0; ni < 4; ni++) {
        int bk = bkb + ni * 16;
        int b = bk >> 6, o = bk & 63;
        out[(size_t)b * 65536 + n2 * 64 + o] =
            a1v[ni] * acc[mi][ni][reg] + a2v[ni] + a3v[ni] * gg + bb;
      }
    }
  }
}

extern "C" void kernel_launch(void* const* d_in, const int* in_sizes, int n_in,
                              void* d_out, int out_size, void* d_ws, size_t ws_size,
                              hipStream_t stream) {
  const float* x    = (const float*)d_in[0];
  const float* Alog = (const float*)d_in[1];
  const float* W1   = (const float*)d_in[2];
  const float* WV   = (const float*)d_in[3];
  const float* g2   = (const float*)d_in[4];
  const float* b2   = (const float*)d_in[5];
  float* out = (float*)d_out;                       // fp32 output, 64 MiB
  char* ws = (char*)d_ws;

  u16*   xln = (u16*)(ws);                          // 32 MiB: [16384][1024] bf16
  u16*   Wt  = (u16*)(ws + 33554432ull);            //  8 MiB: [1024][4096] bf16 (dead after k_gemm1d)
  float* e1  = (float*)(ws + 33554432ull);          // 64 KiB, overlays Wt (written k_post > last Wt read)
  float* e2  = (float*)(ws + 33619968ull);          // 64 KiB
  float* e3  = (float*)(ws + 33685504ull);          // 64 KiB
  u16*   Dt  = (u16*)(ws + 41943040ull);            //  2 MiB: [1024][1024] bf16 (gamma-folded)
  float* r   = (float*)(ws + 44040192ull);          //  4 KiB
  float* gAc = (float*)(ws + 44044288ull);          //  4 KiB
  float* bAc = (float*)(ws + 44048384ull);          //  4 KiB

  k_pre<<<dim3(2048), dim3(256), 0, stream>>>(Alog, r, W1, WV, Wt);
  k_gemm1d<<<dim3(128, 4), dim3(512), 0, stream>>>(x, Wt, xln);
  k_post<<<dim3(2048), dim3(256), 0, stream>>>(Alog, r, g2, b2, Dt, gAc, bAc, xln, e1, e2, e3);
  k_gemm2g<<<dim3(128, 8), dim3(256), 0, stream>>>(Dt, xln, e1, e2, e3, gAc, bAc, out);
}

// Round 11
// 222.510 us; speedup vs baseline: 1.0440x; 1.0213x over previous
//
#include <hip/hip_runtime.h>
#include <hip/hip_fp16.h>
#include <hip/hip_bf16.h>
#include <math.h>

#define NDIM 1024
#define KDIM 64
#define BDIM 256
#define BKDIM 16384

typedef unsigned short u16;
typedef __attribute__((ext_vector_type(8))) short bf16x8;
typedef __attribute__((ext_vector_type(4))) short bf16x4;
typedef __attribute__((ext_vector_type(4))) float f32x4;

__device__ __forceinline__ float bf2f(u16 u) {
  union { unsigned u; float f; } x; x.u = ((unsigned)u) << 16; return x.f;
}
__device__ __forceinline__ u16 f2bf(float f) {
  union { float f; unsigned u; } x; x.f = f;
  unsigned u = x.u;
  u += 0x7fffu + ((u >> 16) & 1u);   // RNE
  return (u16)(u >> 16);
}
// native RNE f32->bf16 (gfx950 HW convert; bit-identical to f2bf for finite x)
__device__ __forceinline__ u16 f2bf_n(float f) {
  union { __hip_bfloat16 b; u16 u; } c;
  c.b = __float2bfloat16(f);
  return c.u;
}

// async 16B global->LDS (DMA, no VGPR roundtrip). LDS side must be
// wave-uniform base + lane*16; global side is per-lane (free gather).
__device__ __forceinline__ void async16(const u16* g, u16* s) {
  __builtin_amdgcn_global_load_lds(
      (const __attribute__((address_space(1))) unsigned int*)g,
      (__attribute__((address_space(3))) unsigned int*)s,
      16, 0, 0);
}

// ------ K_PRE: blocks [0,1024) = row logsumexp of A_logits/T;
//               blocks [1024,2048) = W sinkhorn (verbatim bodies, merged to
//               cut a launch gap; both depend on nothing). --------------------
__global__ __launch_bounds__(256) void k_pre(const float* __restrict__ Alog,
                                             float* __restrict__ r,
                                             const float* __restrict__ W1,
                                             const float* __restrict__ WV,
                                             u16* __restrict__ Wt) {
  __shared__ float sred[256];
  __shared__ float sla[64 * 65];
  int t = threadIdx.x;
  if (blockIdx.x < 1024) {
    // ---- row logsumexp ----
    int m = blockIdx.x;
    float v[4], mx = -3.0e38f;
#pragma unroll
    for (int j = 0; j < 4; j++) {
      v[j] = Alog[m * NDIM + t + j * 256] * 5.0f;
      mx = fmaxf(mx, v[j]);
    }
    sred[t] = mx; __syncthreads();
    for (int s = 128; s > 0; s >>= 1) { if (t < s) sred[t] = fmaxf(sred[t], sred[t + s]); __syncthreads(); }
    float bm = sred[0]; __syncthreads();
    float sm = 0.f;
#pragma unroll
    for (int j = 0; j < 4; j++) sm += __expf(v[j] - bm);
    sred[t] = sm; __syncthreads();
    for (int s = 128; s > 0; s >>= 1) { if (t < s) sred[t] += sred[t + s]; __syncthreads(); }
    if (t == 0) r[m] = bm + __logf(sred[0]);
  } else {
    // ---- W_logits = W1@WV, per-block sinkhorn, Wt[t][o][i] bf16 ----
    int tb = blockIdx.x - 1024;
    int d = t >> 2, q = t & 3;      // row d, col segment q*16..q*16+15
    float w1[8];
#pragma unroll
    for (int k = 0; k < 8; k++) w1[k] = W1[tb * 8 + k];
    float la[16];
#pragma unroll
    for (int j = 0; j < 16; j++) la[j] = 0.f;
#pragma unroll
    for (int k = 0; k < 8; k++) {
      float wk = w1[k];
      const float4* base = (const float4*)&WV[k * 4096 + d * 64 + q * 16];
#pragma unroll
      for (int v = 0; v < 4; v++) {
        float4 f = base[v];
        la[v * 4 + 0] += wk * f.x; la[v * 4 + 1] += wk * f.y;
        la[v * 4 + 2] += wk * f.z; la[v * 4 + 3] += wk * f.w;
      }
    }
    float mx = -3.0e38f;
#pragma unroll
    for (int j = 0; j < 16; j++) { la[j] *= 5.0f; mx = fmaxf(mx, la[j]); }
    float sm = 0.f;
#pragma unroll
    for (int j = 0; j < 16; j++) sm += __expf(la[j] - mx);
    for (int off = 1; off < 4; off <<= 1) {   // combine 4 lanes of a row
      float mo = __shfl_xor(mx, off), so = __shfl_xor(sm, off);
      float mn = fmaxf(mx, mo);
      sm = sm * __expf(mx - mn) + so * __expf(mo - mn);
      mx = mn;
    }
    float rl = mx + __logf(sm);
#pragma unroll
    for (int j = 0; j < 16; j++) sla[d * 65 + q * 16 + j] = la[j] - rl;
    __syncthreads();
    int e = t >> 2, jj = t & 3;     // col e, row segment jj*16..jj*16+15
    float lb[16]; float m2 = -3.0e38f;
#pragma unroll
    for (int i = 0; i < 16; i++) { lb[i] = sla[(jj * 16 + i) * 65 + e]; m2 = fmaxf(m2, lb[i]); }
    float s2 = 0.f;
#pragma unroll
    for (int i = 0; i < 16; i++) s2 += __expf(lb[i] - m2);
    for (int off = 1; off < 4; off <<= 1) {
      float mo = __shfl_xor(m2, off), so = __shfl_xor(s2, off);
      float mn = fmaxf(m2, mo);
      s2 = s2 * __expf(m2 - mn) + so * __expf(mo - mn);
      m2 = mn;
    }
    float cl = m2 + __logf(s2);
#pragma unroll
    for (int i = 0; i < 16; i++)
      Wt[tb * 4096 + e * 64 + jj * 16 + i] = f2bf(__expf(lb[i] - cl));  // Wt[t][o][i]=W[i][o]
  }
}

// ------ K4 v7: x_local = x@W, row-major xln[bk][m] bf16. Round-10 lesson:
// (512,4)'s 128-reg cap left zero headroom for in-flight x loads -> arch
// VGPR 52, ~1 load outstanding, 2.0 TB/s, MfmaUtil 2.7% (pure exposed
// latency, 55us vs ~18us roofline). This version: 256-thr blocks (h moved
// to blockIdx.y; same total threads/work/stores/XCD-grouping), cap raised
// to ~170 via (256,3), and the loop is split into two phases that issue
// 8 independent float4 loads into a named batch BEFORE any use, pinned by
// sched_barrier(0). 12 waves/CU x 8KB in flight >> the ~25KB/CU needed to
// saturate HBM.
__global__ __launch_bounds__(256, 3) void k_gemm1e(const float* __restrict__ x,
                                                   const u16* __restrict__ Wt,
                                                   u16* __restrict__ xln) {
  int bx = blockIdx.x, by = blockIdx.y, t = threadIdx.x;
  int bt = by >> 1, h = by & 1;         // b-chunk, n-half
  int n8 = (bx & 15) * 8 + (bx >> 4);   // bijective; line-group g = bx&15
  int w = t >> 6, l = t & 63, q = l >> 4, lr = l & 15;
  int nb = n8 * 8 + h * 4;
  const float* xb = x + (size_t)(bt * 64 + w * 16 + lr) * 65536;
  f32x4 acc[4][4] = {};
#pragma unroll
  for (int ph = 0; ph < 2; ph++) {
    // phase load batch: 8 independent 16B loads (2 n x 2 ks x 2 halves)
    float4 xv[2][2][2];
#pragma unroll
    for (int npl = 0; npl < 2; npl++) {
      int n = nb + ph * 2 + npl;
#pragma unroll
      for (int ks = 0; ks < 2; ks++) {
        const float* xr = xb + n * 64 + ks * 32 + q * 8;
        xv[npl][ks][0] = *(const float4*)xr;
        xv[npl][ks][1] = *(const float4*)(xr + 4);
      }
    }
    __builtin_amdgcn_sched_barrier(0);   // loads stay issued above compute
#pragma unroll
    for (int npl = 0; npl < 2; npl++) {
      int np = ph * 2 + npl;
      int n = nb + np;
#pragma unroll
      for (int ks = 0; ks < 2; ks++) {
        float4 v0 = xv[npl][ks][0], v1 = xv[npl][ks][1];
        float vf[8] = {v0.x, v0.y, v0.z, v0.w, v1.x, v1.y, v1.z, v1.w};
        bf16x8 ah, al;
#pragma unroll
        for (int j = 0; j < 8; j++) {
          u16 hh = f2bf_n(vf[j]);
          ah[j] = (short)hh;
          al[j] = (short)f2bf_n(vf[j] - bf2f(hh));
        }
#pragma unroll
        for (int ni = 0; ni < 4; ni++) {
          bf16x8 bfr = *(const bf16x8*)&Wt[(size_t)n * 4096 + (ni * 16 + lr) * 64 + ks * 32 + q * 8];
          acc[np][ni] = __builtin_amdgcn_mfma_f32_16x16x32_bf16(ah, bfr, acc[np][ni], 0, 0, 0);
          acc[np][ni] = __builtin_amdgcn_mfma_f32_16x16x32_bf16(al, bfr, acc[np][ni], 0, 0, 0);
        }
      }
    }
  }
#pragma unroll
  for (int ni = 0; ni < 4; ni++) {
#pragma unroll
    for (int reg = 0; reg < 4; reg++) {
      int bk = (bt * 64 + w * 16 + q * 4 + reg) * 64 + ni * 16 + lr;
      bf16x4 o;
#pragma unroll
      for (int np = 0; np < 4; np++) o[np] = (short)f2bf_n(acc[np][ni][reg]);
      *(bf16x4*)&xln[(size_t)bk * 1024 + nb] = o;   // 8B half-chunk of row bk
    }
  }
}

// ------ K_POST (unchanged): col logsumexp+Dt'/gA/bA ∪ LN stats. -------------
__global__ __launch_bounds__(256) void k_post(const float* __restrict__ Alog,
                                              const float* __restrict__ r,
                                              const float* __restrict__ g2,
                                              const float* __restrict__ b2,
                                              u16* __restrict__ Dt,
                                              float* __restrict__ gAc,
                                              float* __restrict__ bAc,
                                              const u16* __restrict__ xln,
                                              float* __restrict__ e1,
                                              float* __restrict__ e2,
                                              float* __restrict__ e3) {
  __shared__ float sred[256];
  int t = threadIdx.x;
  if (blockIdx.x < 1024) {
    // ---- col logsumexp; Dt'[n][m] = gamma[m]*(A[m][n]-1/N); gA; bA ----
    int n = blockIdx.x;
    float v[4], mx = -3.0e38f;
#pragma unroll
    for (int j = 0; j < 4; j++) {
      int m = t + j * 256;
      v[j] = Alog[m * NDIM + n] * 5.0f - r[m];
      mx = fmaxf(mx, v[j]);
    }
    sred[t] = mx; __syncthreads();
    for (int s = 128; s > 0; s >>= 1) { if (t < s) sred[t] = fmaxf(sred[t], sred[t + s]); __syncthreads(); }
    float bm = sred[0]; __syncthreads();
    float sm = 0.f;
#pragma unroll
    for (int j = 0; j < 4; j++) sm += __expf(v[j] - bm);
    sred[t] = sm; __syncthreads();
    for (int s = 128; s > 0; s >>= 1) { if (t < s) sred[t] += sred[t + s]; __syncthreads(); }
    float cn = bm + __logf(sred[0]);
    float ga = 0.f, ba = 0.f;
#pragma unroll
    for (int j = 0; j < 4; j++) {
      int m = t + j * 256;
      float e = __expf(v[j] - cn);
      float gm = g2[m];
      Dt[n * NDIM + m] = f2bf(gm * (e - 0.0009765625f));
      ga += gm * e; ba += b2[m] * e;
    }
    __syncthreads();
    sred[t] = ga; __syncthreads();
    for (int s = 128; s > 0; s >>= 1) { if (t < s) sred[t] += sred[t + s]; __syncthreads(); }
    if (t == 0) gAc[n] = sred[0];
    __syncthreads();
    sred[t] = ba; __syncthreads();
    for (int s = 128; s > 0; s >>= 1) { if (t < s) sred[t] += sred[t + s]; __syncthreads(); }
    if (t == 0) bAc[n] = sred[0];
  } else {
    // ---- LN stats per bk row -> e1/e2/e3 ----
    int row = (blockIdx.x - 1024) * 16 + (t >> 4);
    int c = t & 15;
    const u16* xr = xln + (size_t)row * 1024 + c * 8;
    float S = 0.f, Q = 0.f, W = 0.f;
#pragma unroll
    for (int j = 0; j < 8; j++) {
      bf16x8 v = *(const bf16x8*)&xr[j * 128];
      const float* gp = g2 + j * 128 + c * 8;
      float4 g0 = *(const float4*)gp;
      float4 g1 = *(const float4*)(gp + 4);
      float gg[8] = {g0.x, g0.y, g0.z, g0.w, g1.x, g1.y, g1.z, g1.w};
#pragma unroll
      for (int k = 0; k < 8; k++) {
        float f = bf2f((u16)v[k]);
        S += f; Q += f * f; W += f * gg[k];
      }
    }
#pragma unroll
    for (int off = 1; off < 16; off <<= 1) {
      S += __shfl_xor(S, off);
      Q += __shfl_xor(Q, off);
      W += __shfl_xor(W, off);
    }
    if (c == 0) {
      float m_ = S * (1.0f / 1024.0f);
      float var = Q * (1.0f / 1024.0f) - m_ * m_;
      float a = rsqrtf(var + 1e-5f);
      e1[row] = a;
      e2[row] = a * W * (1.0f / 1024.0f);
      e3[row] = -a * m_;
    }
  }
}

// ------ K6 v7 (unchanged — proven 52.5us / 0-conflict / 88-VGPR config). ----
__global__ __launch_bounds__(256) void k_gemm2g(const u16* __restrict__ Dt,
                                                const u16* __restrict__ xln,
                                                const float* __restrict__ e1,
                                                const float* __restrict__ e2,
                                                const float* __restrict__ e3,
                                                const float* __restrict__ gAc,
                                                const float* __restrict__ bAc,
                                                float* __restrict__ out) {
  __shared__ __align__(16) u16 lA[128 * 64];  // [n2_local][m], swizzled
  __shared__ __align__(16) u16 lB[128 * 64];  // [bk_local][m], swizzled
  int bkt = blockIdx.x, n2t = blockIdx.y;
  int t = threadIdx.x, w = t >> 6, l = t & 63;
  int q = l >> 4, lr = l & 15;
  int rr = l >> 3;                 // row within 8-row group (0..7)
  int cc = (l & 7) ^ rr;           // logical chunk this lane fetches
  const u16* gAp = Dt  + (size_t)(n2t * 128) * NDIM + cc * 8;
  const u16* gBp = xln + (size_t)(bkt * 128) * NDIM + cc * 8;
  f32x4 acc[4][4] = {};
  for (int kt = 0; kt < 16; kt++) {
#pragma unroll
    for (int j = 0; j < 4; j++) {
      int ci = j * 4 + w;
      int row = ci * 8 + rr;
      async16(gAp + (size_t)row * NDIM + kt * 64, &lA[ci * 512 + l * 8]);
      async16(gBp + (size_t)row * NDIM + kt * 64, &lB[ci * 512 + l * 8]);
    }
    __syncthreads();   // drains vmcnt (global_load_lds) per barrier semantics
#pragma unroll
    for (int ks = 0; ks < 2; ks++) {
      int pc = ((ks * 4 + q) ^ (lr & 7)) * 8;   // physical chunk offset (halves)
      bf16x8 af[4], bfr[4];
#pragma unroll
      for (int mi = 0; mi < 4; mi++)
        af[mi] = *(const bf16x8*)&lA[((w >> 1) * 64 + mi * 16 + lr) * 64 + pc];
#pragma unroll
      for (int ni = 0; ni < 4; ni++)
        bfr[ni] = *(const bf16x8*)&lB[((w & 1) * 64 + ni * 16 + lr) * 64 + pc];
#pragma unroll
      for (int mi = 0; mi < 4; mi++)
#pragma unroll
        for (int ni = 0; ni < 4; ni++)
          acc[mi][ni] = __builtin_amdgcn_mfma_f32_16x16x32_bf16(af[mi], bfr[ni], acc[mi][ni], 0, 0, 0);
    }
    __syncthreads();   // tile consumed before next iter's DMA overwrites
  }
  // Stage epilogue operands into dead lA (2.5KB): [0)e1 [128)e2 [256)e3 [384)gA [512)bA
  float* sE = (float*)lA;
  if (t < 128) {
    sE[t]       = e1[bkt * 128 + t];
    sE[128 + t] = e2[bkt * 128 + t];
    sE[256 + t] = e3[bkt * 128 + t];
    sE[384 + t] = gAc[n2t * 128 + t];
    sE[512 + t] = bAc[n2t * 128 + t];
  }
  __syncthreads();
  // 12 per-bk scalars hoisted once (invariant across the outer n2 loop):
  float a1v[4], a2v[4], a3v[4];
#pragma unroll
  for (int ni = 0; ni < 4; ni++) {
    int bkl = (w & 1) * 64 + ni * 16 + lr;       // local bk 0..127
    a1v[ni] = sE[bkl]; a2v[ni] = sE[128 + bkl]; a3v[ni] = sE[256 + bkl];
  }
  int bkb = bkt * 128 + (w & 1) * 64 + lr;       // bk for ni=0
#pragma unroll
  for (int mi = 0; mi < 4; mi++) {
    __builtin_amdgcn_sched_barrier(0);           // pin sE reads per mi group
#pragma unroll
    for (int reg = 0; reg < 4; reg++) {
      int n2l = (w >> 1) * 64 + mi * 16 + q * 4 + reg;   // local n2 0..127
      float gg = sE[384 + n2l], bb = sE[512 + n2l];
      int n2 = n2t * 128 + n2l;
#pragma unroll
      for (int ni = 0; ni < 4; ni++) {
        int bk = bkb + ni * 16;
        int b = bk >> 6, o = bk & 63;
        out[(size_t)b * 65536 + n2 * 64 + o] =
            a1v[ni] * acc[mi][ni][reg] + a2v[ni] + a3v[ni] * gg + bb;
      }
    }
  }
}

extern "C" void kernel_launch(void* const* d_in, const int* in_sizes, int n_in,
                              void* d_out, int out_size, void* d_ws, size_t ws_size,
                              hipStream_t stream) {
  const float* x    = (const float*)d_in[0];
  const float* Alog = (const float*)d_in[1];
  const float* W1   = (const float*)d_in[2];
  const float* WV   = (const float*)d_in[3];
  const float* g2   = (const float*)d_in[4];
  const float* b2   = (const float*)d_in[5];
  float* out = (float*)d_out;                       // fp32 output, 64 MiB
  char* ws = (char*)d_ws;

  u16*   xln = (u16*)(ws);                          // 32 MiB: [16384][1024] bf16
  u16*   Wt  = (u16*)(ws + 33554432ull);            //  8 MiB: [1024][4096] bf16 (dead after k_gemm1e)
  float* e1  = (float*)(ws + 33554432ull);          // 64 KiB, overlays Wt (written k_post > last Wt read)
  float* e2  = (float*)(ws + 33619968ull);          // 64 KiB
  float* e3  = (float*)(ws + 33685504ull);          // 64 KiB
  u16*   Dt  = (u16*)(ws + 41943040ull);            //  2 MiB: [1024][1024] bf16 (gamma-folded)
  float* r   = (float*)(ws + 44040192ull);          //  4 KiB
  float* gAc = (float*)(ws + 44044288ull);          //  4 KiB
  float* bAc = (float*)(ws + 44048384ull);          //  4 KiB

  k_pre<<<dim3(2048), dim3(256), 0, stream>>>(Alog, r, W1, WV, Wt);
  k_gemm1e<<<dim3(128, 8), dim3(256), 0, stream>>>(x, Wt, xln);
  k_post<<<dim3(2048), dim3(256), 0, stream>>>(Alog, r, g2, b2, Dt, gAc, bAc, xln, e1, e2, e3);
  k_gemm2g<<<dim3(128, 8), dim3(256), 0, stream>>>(Dt, xln, e1, e2, e3, gAc, bAc, out);
}

// Round 12
// 216.915 us; speedup vs baseline: 1.0710x; 1.0258x over previous
//
#include <hip/hip_runtime.h>
#include <hip/hip_fp16.h>
#include <hip/hip_bf16.h>
#include <math.h>

#define NDIM 1024
#define KDIM 64
#define BDIM 256
#define BKDIM 16384

typedef unsigned short u16;
typedef __attribute__((ext_vector_type(8))) short bf16x8;
typedef __attribute__((ext_vector_type(4))) short bf16x4;
typedef __attribute__((ext_vector_type(4))) float f32x4;

__device__ __forceinline__ float bf2f(u16 u) {
  union { unsigned u; float f; } x; x.u = ((unsigned)u) << 16; return x.f;
}
__device__ __forceinline__ u16 f2bf(float f) {
  union { float f; unsigned u; } x; x.f = f;
  unsigned u = x.u;
  u += 0x7fffu + ((u >> 16) & 1u);   // RNE
  return (u16)(u >> 16);
}
// native RNE f32->bf16 (gfx950 HW convert; bit-identical to f2bf for finite x)
__device__ __forceinline__ u16 f2bf_n(float f) {
  union { __hip_bfloat16 b; u16 u; } c;
  c.b = __float2bfloat16(f);
  return c.u;
}

// async 16B global->LDS (DMA, no VGPR roundtrip). LDS side must be
// wave-uniform base + lane*16; global side is per-lane (free gather).
__device__ __forceinline__ void async16(const u16* g, u16* s) {
  __builtin_amdgcn_global_load_lds(
      (const __attribute__((address_space(1))) unsigned int*)g,
      (__attribute__((address_space(3))) unsigned int*)s,
      16, 0, 0);
}

// ------ K_PRE: blocks [0,1024) = row logsumexp of A_logits/T;
//               blocks [1024,2048) = W sinkhorn (verbatim bodies, merged to
//               cut a launch gap; both depend on nothing). --------------------
__global__ __launch_bounds__(256) void k_pre(const float* __restrict__ Alog,
                                             float* __restrict__ r,
                                             const float* __restrict__ W1,
                                             const float* __restrict__ WV,
                                             u16* __restrict__ Wt) {
  __shared__ float sred[256];
  __shared__ float sla[64 * 65];
  int t = threadIdx.x;
  if (blockIdx.x < 1024) {
    // ---- row logsumexp ----
    int m = blockIdx.x;
    float v[4], mx = -3.0e38f;
#pragma unroll
    for (int j = 0; j < 4; j++) {
      v[j] = Alog[m * NDIM + t + j * 256] * 5.0f;
      mx = fmaxf(mx, v[j]);
    }
    sred[t] = mx; __syncthreads();
    for (int s = 128; s > 0; s >>= 1) { if (t < s) sred[t] = fmaxf(sred[t], sred[t + s]); __syncthreads(); }
    float bm = sred[0]; __syncthreads();
    float sm = 0.f;
#pragma unroll
    for (int j = 0; j < 4; j++) sm += __expf(v[j] - bm);
    sred[t] = sm; __syncthreads();
    for (int s = 128; s > 0; s >>= 1) { if (t < s) sred[t] += sred[t + s]; __syncthreads(); }
    if (t == 0) r[m] = bm + __logf(sred[0]);
  } else {
    // ---- W_logits = W1@WV, per-block sinkhorn, Wt[t][o][i] bf16 ----
    int tb = blockIdx.x - 1024;
    int d = t >> 2, q = t & 3;      // row d, col segment q*16..q*16+15
    float w1[8];
#pragma unroll
    for (int k = 0; k < 8; k++) w1[k] = W1[tb * 8 + k];
    float la[16];
#pragma unroll
    for (int j = 0; j < 16; j++) la[j] = 0.f;
#pragma unroll
    for (int k = 0; k < 8; k++) {
      float wk = w1[k];
      const float4* base = (const float4*)&WV[k * 4096 + d * 64 + q * 16];
#pragma unroll
      for (int v = 0; v < 4; v++) {
        float4 f = base[v];
        la[v * 4 + 0] += wk * f.x; la[v * 4 + 1] += wk * f.y;
        la[v * 4 + 2] += wk * f.z; la[v * 4 + 3] += wk * f.w;
      }
    }
    float mx = -3.0e38f;
#pragma unroll
    for (int j = 0; j < 16; j++) { la[j] *= 5.0f; mx = fmaxf(mx, la[j]); }
    float sm = 0.f;
#pragma unroll
    for (int j = 0; j < 16; j++) sm += __expf(la[j] - mx);
    for (int off = 1; off < 4; off <<= 1) {   // combine 4 lanes of a row
      float mo = __shfl_xor(mx, off), so = __shfl_xor(sm, off);
      float mn = fmaxf(mx, mo);
      sm = sm * __expf(mx - mn) + so * __expf(mo - mn);
      mx = mn;
    }
    float rl = mx + __logf(sm);
#pragma unroll
    for (int j = 0; j < 16; j++) sla[d * 65 + q * 16 + j] = la[j] - rl;
    __syncthreads();
    int e = t >> 2, jj = t & 3;     // col e, row segment jj*16..jj*16+15
    float lb[16]; float m2 = -3.0e38f;
#pragma unroll
    for (int i = 0; i < 16; i++) { lb[i] = sla[(jj * 16 + i) * 65 + e]; m2 = fmaxf(m2, lb[i]); }
    float s2 = 0.f;
#pragma unroll
    for (int i = 0; i < 16; i++) s2 += __expf(lb[i] - m2);
    for (int off = 1; off < 4; off <<= 1) {
      float mo = __shfl_xor(m2, off), so = __shfl_xor(s2, off);
      float mn = fmaxf(m2, mo);
      s2 = s2 * __expf(m2 - mn) + so * __expf(mo - mn);
      m2 = mn;
    }
    float cl = m2 + __logf(s2);
#pragma unroll
    for (int i = 0; i < 16; i++)
      Wt[tb * 4096 + e * 64 + jj * 16 + i] = f2bf(__expf(lb[i] - cl));  // Wt[t][o][i]=W[i][o]
  }
}

// ------ K4 v8: x_local = x@W, row-major xln[bk][m] bf16. Round-11 lesson:
// the serial chain was the PER-MFMA global Wt load (32 dependent L2 round
// trips/thread; VGPR 64 showed none were batched). Fix: stage the block's
// 4 Wt n-slices (32KB) into LDS once (8 async16 iters + 1 barrier), with the
// chunk-XOR involution c' = c ^ (row&7) applied on the STAGE SOURCE address
// (async16 writes linearly) and the same XOR on the read side -> 64 lanes
// cover all 32 banks 2-way (free). Main loop then has only batched x loads
// as global traffic; MFMA operands come from LDS.
__global__ __launch_bounds__(256, 3) void k_gemm1f(const float* __restrict__ x,
                                                   const u16* __restrict__ Wt,
                                                   u16* __restrict__ xln) {
  __shared__ __align__(16) u16 lWt[4 * 4096];   // 32KB: [n_local][row][chunk'], swizzled
  int bx = blockIdx.x, by = blockIdx.y, t = threadIdx.x;
  int bt = by >> 1, h = by & 1;         // b-chunk, n-half
  int n8 = (bx & 15) * 8 + (bx >> 4);   // bijective; line-group g = bx&15
  int w = t >> 6, l = t & 63, q = l >> 4, lr = l & 15;
  int nb = n8 * 8 + h * 4;
  // ---- stage Wt[nb..nb+3] -> LDS (source pre-swizzled, dest linear) ----
#pragma unroll
  for (int it = 0; it < 8; it++) {
    int ci = it * 256 + t;              // chunk id 0..2047 (16B chunks)
    int n = ci >> 9;                    // 512 chunks per n-slice
    int rem = ci & 511;
    int row = rem >> 3;                 // o-row 0..63 (128B each)
    int cd = rem & 7;                   // dest chunk within row
    int cs = cd ^ (row & 7);            // involution: source chunk
    async16(Wt + (size_t)(nb + n) * 4096 + row * 64 + cs * 8, &lWt[ci * 8]);
  }
  const float* xb = x + (size_t)(bt * 64 + w * 16 + lr) * 65536;
  __syncthreads();   // drains vmcnt -> lWt ready

  f32x4 acc[4][4] = {};
#pragma unroll
  for (int ph = 0; ph < 2; ph++) {
    // phase load batch: 8 independent 16B x loads (2 n x 2 ks x 2 halves)
    float4 xv[2][2][2];
#pragma unroll
    for (int npl = 0; npl < 2; npl++) {
      int n = nb + ph * 2 + npl;
#pragma unroll
      for (int ks = 0; ks < 2; ks++) {
        const float* xr = xb + n * 64 + ks * 32 + q * 8;
        xv[npl][ks][0] = *(const float4*)xr;
        xv[npl][ks][1] = *(const float4*)(xr + 4);
      }
    }
#pragma unroll
    for (int npl = 0; npl < 2; npl++) {
      int np = ph * 2 + npl;
#pragma unroll
      for (int ks = 0; ks < 2; ks++) {
        float4 v0 = xv[npl][ks][0], v1 = xv[npl][ks][1];
        float vf[8] = {v0.x, v0.y, v0.z, v0.w, v1.x, v1.y, v1.z, v1.w};
        bf16x8 ah, al;
#pragma unroll
        for (int j = 0; j < 8; j++) {
          u16 hh = f2bf_n(vf[j]);
          ah[j] = (short)hh;
          al[j] = (short)f2bf_n(vf[j] - bf2f(hh));
        }
#pragma unroll
        for (int ni = 0; ni < 4; ni++) {
          int row = ni * 16 + lr;
          int cp = (ks * 4 + q) ^ (lr & 7);   // read-side swizzled chunk
          bf16x8 bfr = *(const bf16x8*)&lWt[np * 4096 + row * 64 + cp * 8];
          acc[np][ni] = __builtin_amdgcn_mfma_f32_16x16x32_bf16(ah, bfr, acc[np][ni], 0, 0, 0);
          acc[np][ni] = __builtin_amdgcn_mfma_f32_16x16x32_bf16(al, bfr, acc[np][ni], 0, 0, 0);
        }
      }
    }
  }
#pragma unroll
  for (int ni = 0; ni < 4; ni++) {
#pragma unroll
    for (int reg = 0; reg < 4; reg++) {
      int bk = (bt * 64 + w * 16 + q * 4 + reg) * 64 + ni * 16 + lr;
      bf16x4 o;
#pragma unroll
      for (int np = 0; np < 4; np++) o[np] = (short)f2bf_n(acc[np][ni][reg]);
      *(bf16x4*)&xln[(size_t)bk * 1024 + nb] = o;   // 8B half-chunk of row bk
    }
  }
}

// ------ K_POST (unchanged): col logsumexp+Dt'/gA/bA ∪ LN stats. -------------
__global__ __launch_bounds__(256) void k_post(const float* __restrict__ Alog,
                                              const float* __restrict__ r,
                                              const float* __restrict__ g2,
                                              const float* __restrict__ b2,
                                              u16* __restrict__ Dt,
                                              float* __restrict__ gAc,
                                              float* __restrict__ bAc,
                                              const u16* __restrict__ xln,
                                              float* __restrict__ e1,
                                              float* __restrict__ e2,
                                              float* __restrict__ e3) {
  __shared__ float sred[256];
  int t = threadIdx.x;
  if (blockIdx.x < 1024) {
    // ---- col logsumexp; Dt'[n][m] = gamma[m]*(A[m][n]-1/N); gA; bA ----
    int n = blockIdx.x;
    float v[4], mx = -3.0e38f;
#pragma unroll
    for (int j = 0; j < 4; j++) {
      int m = t + j * 256;
      v[j] = Alog[m * NDIM + n] * 5.0f - r[m];
      mx = fmaxf(mx, v[j]);
    }
    sred[t] = mx; __syncthreads();
    for (int s = 128; s > 0; s >>= 1) { if (t < s) sred[t] = fmaxf(sred[t], sred[t + s]); __syncthreads(); }
    float bm = sred[0]; __syncthreads();
    float sm = 0.f;
#pragma unroll
    for (int j = 0; j < 4; j++) sm += __expf(v[j] - bm);
    sred[t] = sm; __syncthreads();
    for (int s = 128; s > 0; s >>= 1) { if (t < s) sred[t] += sred[t + s]; __syncthreads(); }
    float cn = bm + __logf(sred[0]);
    float ga = 0.f, ba = 0.f;
#pragma unroll
    for (int j = 0; j < 4; j++) {
      int m = t + j * 256;
      float e = __expf(v[j] - cn);
      float gm = g2[m];
      Dt[n * NDIM + m] = f2bf(gm * (e - 0.0009765625f));
      ga += gm * e; ba += b2[m] * e;
    }
    __syncthreads();
    sred[t] = ga; __syncthreads();
    for (int s = 128; s > 0; s >>= 1) { if (t < s) sred[t] += sred[t + s]; __syncthreads(); }
    if (t == 0) gAc[n] = sred[0];
    __syncthreads();
    sred[t] = ba; __syncthreads();
    for (int s = 128; s > 0; s >>= 1) { if (t < s) sred[t] += sred[t + s]; __syncthreads(); }
    if (t == 0) bAc[n] = sred[0];
  } else {
    // ---- LN stats per bk row -> e1/e2/e3 ----
    int row = (blockIdx.x - 1024) * 16 + (t >> 4);
    int c = t & 15;
    const u16* xr = xln + (size_t)row * 1024 + c * 8;
    float S = 0.f, Q = 0.f, W = 0.f;
#pragma unroll
    for (int j = 0; j < 8; j++) {
      bf16x8 v = *(const bf16x8*)&xr[j * 128];
      const float* gp = g2 + j * 128 + c * 8;
      float4 g0 = *(const float4*)gp;
      float4 g1 = *(const float4*)(gp + 4);
      float gg[8] = {g0.x, g0.y, g0.z, g0.w, g1.x, g1.y, g1.z, g1.w};
#pragma unroll
      for (int k = 0; k < 8; k++) {
        float f = bf2f((u16)v[k]);
        S += f; Q += f * f; W += f * gg[k];
      }
    }
#pragma unroll
    for (int off = 1; off < 16; off <<= 1) {
      S += __shfl_xor(S, off);
      Q += __shfl_xor(Q, off);
      W += __shfl_xor(W, off);
    }
    if (c == 0) {
      float m_ = S * (1.0f / 1024.0f);
      float var = Q * (1.0f / 1024.0f) - m_ * m_;
      float a = rsqrtf(var + 1e-5f);
      e1[row] = a;
      e2[row] = a * W * (1.0f / 1024.0f);
      e3[row] = -a * m_;
    }
  }
}

// ------ K6 v7 (unchanged — proven 52.5us / 0-conflict / 88-VGPR config). ----
__global__ __launch_bounds__(256) void k_gemm2g(const u16* __restrict__ Dt,
                                                const u16* __restrict__ xln,
                                                const float* __restrict__ e1,
                                                const float* __restrict__ e2,
                                                const float* __restrict__ e3,
                                                const float* __restrict__ gAc,
                                                const float* __restrict__ bAc,
                                                float* __restrict__ out) {
  __shared__ __align__(16) u16 lA[128 * 64];  // [n2_local][m], swizzled
  __shared__ __align__(16) u16 lB[128 * 64];  // [bk_local][m], swizzled
  int bkt = blockIdx.x, n2t = blockIdx.y;
  int t = threadIdx.x, w = t >> 6, l = t & 63;
  int q = l >> 4, lr = l & 15;
  int rr = l >> 3;                 // row within 8-row group (0..7)
  int cc = (l & 7) ^ rr;           // logical chunk this lane fetches
  const u16* gAp = Dt  + (size_t)(n2t * 128) * NDIM + cc * 8;
  const u16* gBp = xln + (size_t)(bkt * 128) * NDIM + cc * 8;
  f32x4 acc[4][4] = {};
  for (int kt = 0; kt < 16; kt++) {
#pragma unroll
    for (int j = 0; j < 4; j++) {
      int ci = j * 4 + w;
      int row = ci * 8 + rr;
      async16(gAp + (size_t)row * NDIM + kt * 64, &lA[ci * 512 + l * 8]);
      async16(gBp + (size_t)row * NDIM + kt * 64, &lB[ci * 512 + l * 8]);
    }
    __syncthreads();   // drains vmcnt (global_load_lds) per barrier semantics
#pragma unroll
    for (int ks = 0; ks < 2; ks++) {
      int pc = ((ks * 4 + q) ^ (lr & 7)) * 8;   // physical chunk offset (halves)
      bf16x8 af[4], bfr[4];
#pragma unroll
      for (int mi = 0; mi < 4; mi++)
        af[mi] = *(const bf16x8*)&lA[((w >> 1) * 64 + mi * 16 + lr) * 64 + pc];
#pragma unroll
      for (int ni = 0; ni < 4; ni++)
        bfr[ni] = *(const bf16x8*)&lB[((w & 1) * 64 + ni * 16 + lr) * 64 + pc];
#pragma unroll
      for (int mi = 0; mi < 4; mi++)
#pragma unroll
        for (int ni = 0; ni < 4; ni++)
          acc[mi][ni] = __builtin_amdgcn_mfma_f32_16x16x32_bf16(af[mi], bfr[ni], acc[mi][ni], 0, 0, 0);
    }
    __syncthreads();   // tile consumed before next iter's DMA overwrites
  }
  // Stage epilogue operands into dead lA (2.5KB): [0)e1 [128)e2 [256)e3 [384)gA [512)bA
  float* sE = (float*)lA;
  if (t < 128) {
    sE[t]       = e1[bkt * 128 + t];
    sE[128 + t] = e2[bkt * 128 + t];
    sE[256 + t] = e3[bkt * 128 + t];
    sE[384 + t] = gAc[n2t * 128 + t];
    sE[512 + t] = bAc[n2t * 128 + t];
  }
  __syncthreads();
  // 12 per-bk scalars hoisted once (invariant across the outer n2 loop):
  float a1v[4], a2v[4], a3v[4];
#pragma unroll
  for (int ni = 0; ni < 4; ni++) {
    int bkl = (w & 1) * 64 + ni * 16 + lr;       // local bk 0..127
    a1v[ni] = sE[bkl]; a2v[ni] = sE[128 + bkl]; a3v[ni] = sE[256 + bkl];
  }
  int bkb = bkt * 128 + (w & 1) * 64 + lr;       // bk for ni=0
#pragma unroll
  for (int mi = 0; mi < 4; mi++) {
    __builtin_amdgcn_sched_barrier(0);           // pin sE reads per mi group
#pragma unroll
    for (int reg = 0; reg < 4; reg++) {
      int n2l = (w >> 1) * 64 + mi * 16 + q * 4 + reg;   // local n2 0..127
      float gg = sE[384 + n2l], bb = sE[512 + n2l];
      int n2 = n2t * 128 + n2l;
#pragma unroll
      for (int ni = 0; ni < 4; ni++) {
        int bk = bkb + ni * 16;
        int b = bk >> 6, o = bk & 63;
        out[(size_t)b * 65536 + n2 * 64 + o] =
            a1v[ni] * acc[mi][ni][reg] + a2v[ni] + a3v[ni] * gg + bb;
      }
    }
  }
}

extern "C" void kernel_launch(void* const* d_in, const int* in_sizes, int n_in,
                              void* d_out, int out_size, void* d_ws, size_t ws_size,
                              hipStream_t stream) {
  const float* x    = (const float*)d_in[0];
  const float* Alog = (const float*)d_in[1];
  const float* W1   = (const float*)d_in[2];
  const float* WV   = (const float*)d_in[3];
  const float* g2   = (const float*)d_in[4];
  const float* b2   = (const float*)d_in[5];
  float* out = (float*)d_out;                       // fp32 output, 64 MiB
  char* ws = (char*)d_ws;

  u16*   xln = (u16*)(ws);                          // 32 MiB: [16384][1024] bf16
  u16*   Wt  = (u16*)(ws + 33554432ull);            //  8 MiB: [1024][4096] bf16 (dead after k_gemm1f)
  float* e1  = (float*)(ws + 33554432ull);          // 64 KiB, overlays Wt (written k_post > last Wt read)
  float* e2  = (float*)(ws + 33619968ull);          // 64 KiB
  float* e3  = (float*)(ws + 33685504ull);          // 64 KiB
  u16*   Dt  = (u16*)(ws + 41943040ull);            //  2 MiB: [1024][1024] bf16 (gamma-folded)
  float* r   = (float*)(ws + 44040192ull);          //  4 KiB
  float* gAc = (float*)(ws + 44044288ull);          //  4 KiB
  float* bAc = (float*)(ws + 44048384ull);          //  4 KiB

  k_pre<<<dim3(2048), dim3(256), 0, stream>>>(Alog, r, W1, WV, Wt);
  k_gemm1f<<<dim3(128, 8), dim3(256), 0, stream>>>(x, Wt, xln);
  k_post<<<dim3(2048), dim3(256), 0, stream>>>(Alog, r, g2, b2, Dt, gAc, bAc, xln, e1, e2, e3);
  k_gemm2g<<<dim3(128, 8), dim3(256), 0, stream>>>(Dt, xln, e1, e2, e3, gAc, bAc, out);
}